// Round 10
// baseline (70.710 us; speedup 1.0000x reference)
//
#include <hip/hip_runtime.h>
#include <hip/hip_bf16.h>

constexpr int kNodes  = 50000;
constexpr int kEdges  = 600000;
constexpr int kD      = 128;
constexpr int kStrips = kNodes / 16;               // 3125 gemm strips
constexpr int kStride = 64;                        // CSR segment capacity (max deg ~35)

// Bucket geometry (R8/R9's cheap scatter role)
constexpr int kNB   = 400;                         // coarse dst-buckets
constexpr int kNPB  = 125;                         // nodes per bucket
constexpr int kCap  = 2048;                        // slots per bucket (mean 1500)
constexpr int kEPB  = 4096;                        // edges per bucket-role block
constexpr int kBktBlocks  = (kEdges + kEPB - 1) / kEPB;   // 147
constexpr int kGemmBlocks = 768;                   // persistent gemm blocks
constexpr int kTotalBlocks = kBktBlocks + kGemmBlocks;    // 915

typedef __attribute__((ext_vector_type(8))) short  short8;   // 8 bf16 (A/B frag)
typedef __attribute__((ext_vector_type(4))) float  f32x4;    // C/D frag

__device__ __forceinline__ unsigned short f2bfu(float x) {
    __hip_bfloat16 h = __float2bfloat16(x);                   // RTNE
    return (unsigned short)__builtin_bit_cast(short, h);
}
__device__ __forceinline__ short f2bf(float x) {
    return __builtin_bit_cast(short, __float2bfloat16(x));
}

// ---------------------------------------------------------------------------
// Prep: pack B^T = [U | V]^T as bf16 in FRAGMENT-MAJOR layout (R7 layout,
// unchanged) + zero the padded bucket counters.
// ---------------------------------------------------------------------------
__global__ __launch_bounds__(512) void pack_init(const float* __restrict__ U,
                                                 const float* __restrict__ V,
                                                 short* __restrict__ BTf,
                                                 int* __restrict__ bcnt) {
    const int g = blockIdx.x * 512 + threadIdx.x;
    if (g < 256 * kD) {
        const int c = g >> 7;          // 0..255 (global output col)
        const int k = g & 127;
        const float x = (c < kD) ? U[k * kD + c] : V[k * kD + (c - kD)];
        const int q  = c >> 6;
        const int n  = (c >> 4) & 3;
        const int m  = c & 15;
        const int t  = k >> 5;
        const int kg = (k >> 3) & 3;
        const int ko = k & 7;
        const int lane = kg * 16 + m;
        BTf[((((q * 4 + n) * 4 + t) * 64 + lane) << 3) + ko] = f2bf(x);
    }
    if (g < kNB * 32) bcnt[g] = 0;
}

// ---------------------------------------------------------------------------
// FUSED kernel: persistent-wave MFMA dual GEMM + edge BUCKETING.
//
// gemm role (R10): B-frags register-resident (loaded once per block, R9).
// NEW: (a) SWAPPED mfma operands — mfma(bf, a, acc) yields the transposed
// tile, so each thread holds output ROW row0+m, 4 CONSECUTIVE cols kg*4+j
// -> epilogue is 4 packed 8B uint2 stores per region instead of 16 scalar
// 2B stores (A/B operand lane layouts are symmetric, so the same register
// contents feed either slot; D layout col=lane&15 -> row, (lane>>4)*4+j ->
// col, per the m89-verified mapping).  (b) 2-deep strip software pipeline:
// strip s+1's 8 H-loads are issued before strip s's convert/MFMA/store
// (named haA/haB double buffers, all indices compile-time).
//
// bucket role (unchanged, proven cheap): LDS histogram over 400 coarse
// buckets, one bulk global atomic per (block,bucket), packed u32 stores.
// ---------------------------------------------------------------------------
__global__ __launch_bounds__(256) void gemm_bucket(const float* __restrict__ H,
                                                   const short* __restrict__ BTf,
                                                   const int* __restrict__ esrc,
                                                   const int* __restrict__ edst,
                                                   unsigned short* __restrict__ outb, // d_out u16
                                                   unsigned short* __restrict__ hvb,
                                                   int* __restrict__ bcnt,            // padded x32
                                                   unsigned int* __restrict__ barr) {
    __shared__ int hist[kNB];
    __shared__ int cur[kNB];
    const int bid = blockIdx.x;

    if (bid < kBktBlocks) {
        // ---- bucket role: 4096 edges per block ----
        const int e0 = bid * kEPB;
        for (int i = threadIdx.x; i < kNB; i += 256) hist[i] = 0;
        __syncthreads();
#pragma unroll
        for (int i = 0; i < kEPB / 256; ++i) {
            const int e = e0 + i * 256 + (int)threadIdx.x;
            if (e < kEdges) atomicAdd(&hist[edst[e] / kNPB], 1);
        }
        __syncthreads();
        for (int i = threadIdx.x; i < kNB; i += 256)
            cur[i] = atomicAdd(&bcnt[i * 32], hist[i]);   // bulk range per bucket
        __syncthreads();
#pragma unroll
        for (int i = 0; i < kEPB / 256; ++i) {
            const int e = e0 + i * 256 + (int)threadIdx.x;
            if (e < kEdges) {
                const int d = edst[e];
                const int b = d / kNPB;
                const int slot = atomicAdd(&cur[b], 1);   // LDS atomic
                if (slot < kCap)
                    barr[(size_t)b * kCap + slot] =
                        ((unsigned)(d - b * kNPB) << 16) | (unsigned)esrc[e];
            }
        }
        return;
    }

    // ---- gemm role: persistent wave, register-resident B ----
    const int g  = bid - kBktBlocks;                 // 0..767
    const int s0 = (int)((long)g       * kStrips / kGemmBlocks);
    const int s1 = (int)((long)(g + 1) * kStrips / kGemmBlocks);
    const int quad = threadIdx.x >> 6;               // 0..3 (64-col quarter)
    const int lane = threadIdx.x & 63;
    const int m  = lane & 15;
    const int kg = lane >> 4;                        // 0..3

    // B-frags for this quad: 16 x dwordx4, loaded ONCE (64 VGPRs)
    const short8* bq = reinterpret_cast<const short8*>(BTf)
                     + ((size_t)quad * 16) * 64 + lane;
    short8 bf[4][4];
#pragma unroll
    for (int n = 0; n < 4; ++n)
#pragma unroll
        for (int t = 0; t < 4; ++t)
            bf[n][t] = bq[(n * 4 + t) * 64];

    auto load_ha = [&](int s, float4 (&ha)[4][2]) {
        const float* hbase = H + ((long)s * 16 + m) * kD + kg * 8;
#pragma unroll
        for (int t = 0; t < 4; ++t) {
            ha[t][0] = *reinterpret_cast<const float4*>(hbase + t * 32);
            ha[t][1] = *reinterpret_cast<const float4*>(hbase + t * 32 + 4);
        }
    };

    auto compute_store = [&](int s, float4 (&ha)[4][2]) {
        short8 a[4];
#pragma unroll
        for (int t = 0; t < 4; ++t) {
            a[t][0] = f2bf(ha[t][0].x); a[t][1] = f2bf(ha[t][0].y);
            a[t][2] = f2bf(ha[t][0].z); a[t][3] = f2bf(ha[t][0].w);
            a[t][4] = f2bf(ha[t][1].x); a[t][5] = f2bf(ha[t][1].y);
            a[t][6] = f2bf(ha[t][1].z); a[t][7] = f2bf(ha[t][1].w);
        }

        f32x4 acc[4];
#pragma unroll
        for (int i = 0; i < 4; ++i) acc[i] = (f32x4){0.f, 0.f, 0.f, 0.f};
#pragma unroll
        for (int t = 0; t < 4; ++t)
#pragma unroll
            for (int n = 0; n < 4; ++n)   // SWAPPED operands -> transposed tile
                acc[n] = __builtin_amdgcn_mfma_f32_16x16x32_bf16(bf[n][t], a[t], acc[n], 0, 0, 0);

        // Thread owns row row0+m, cols base + n*16 + kg*4 + (0..3): packed 8B stores.
        const long row0 = (long)s * 16;
        if (quad < 2) {      // hu -> d_out rows (bf16, first 256B of each row)
            unsigned short* rowp = outb + (size_t)(row0 + m) * 256 + quad * 64 + kg * 4;
#pragma unroll
            for (int n = 0; n < 4; ++n) {
                uint2 pk;
                pk.x = ((unsigned)f2bfu(acc[n][1]) << 16) | f2bfu(acc[n][0]);
                pk.y = ((unsigned)f2bfu(acc[n][3]) << 16) | f2bfu(acc[n][2]);
                *reinterpret_cast<uint2*>(rowp + n * 16) = pk;
            }
        } else {             // hv -> ws (bf16)
            unsigned short* rowp = hvb + (size_t)(row0 + m) * kD + (quad - 2) * 64 + kg * 4;
#pragma unroll
            for (int n = 0; n < 4; ++n) {
                uint2 pk;
                pk.x = ((unsigned)f2bfu(acc[n][1]) << 16) | f2bfu(acc[n][0]);
                pk.y = ((unsigned)f2bfu(acc[n][3]) << 16) | f2bfu(acc[n][2]);
                *reinterpret_cast<uint2*>(rowp + n * 16) = pk;
            }
        }
    };

    // 2-deep software pipeline over strips
    float4 haA[4][2], haB[4][2];
    int s = s0;
    if (s >= s1) return;
    load_ha(s, haA);
    for (; s + 1 < s1; s += 2) {
        load_ha(s + 1, haB);
        compute_store(s, haA);
        if (s + 2 < s1) load_ha(s + 2, haA);
        compute_store(s + 1, haB);
    }
    if (s < s1) compute_store(s, haA);
}

// ---------------------------------------------------------------------------
// Bucket -> fixed-stride CSR counting sort (unchanged, ~4us).  LDS-atomic
// slot allocation, plain stores, no global atomics.
// ---------------------------------------------------------------------------
__global__ __launch_bounds__(256) void bucket_sort(const int* __restrict__ bcnt,
                                                   const unsigned int* __restrict__ barr,
                                                   int* __restrict__ cursor,
                                                   unsigned short* __restrict__ csr16) {
    __shared__ int cnt[kNPB];
    const int b = blockIdx.x;
    for (int i = threadIdx.x; i < kNPB; i += 256) cnt[i] = 0;
    __syncthreads();

    const int n = min(bcnt[b * 32], kCap);
    const unsigned int* arr = barr + (size_t)b * kCap;
    for (int i = threadIdx.x; i < n; i += 256) {
        const unsigned int p = arr[i];
        const int dl  = (int)(p >> 16);
        const int src = (int)(p & 0xffffu);
        const int slot = atomicAdd(&cnt[dl], 1);            // LDS atomic
        if (slot < kStride)
            csr16[((size_t)b * kNPB + dl) * kStride + slot] = (unsigned short)src;
    }
    __syncthreads();
    for (int i = threadIdx.x; i < kNPB; i += 256)
        cursor[b * kNPB + i] = cnt[i];
}

// ---------------------------------------------------------------------------
// Aggregation + ReLU.  One wave per node (R7-proven structure); NEW 8-wide
// unroll tier for more outstanding gathers (mean deg 12).
// ---------------------------------------------------------------------------
__global__ __launch_bounds__(256) void aggregate_relu(const unsigned int* __restrict__ hvb,
                                                      const int* __restrict__ cursor,
                                                      const unsigned short* __restrict__ csr16,
                                                      float* __restrict__ out) {
    const int wid  = (int)((blockIdx.x * (long)blockDim.x + threadIdx.x) >> 6);
    const int lane = threadIdx.x & 63;
    if (wid >= kNodes) return;

    const int deg = min(cursor[wid], kStride);          // wave-uniform
    const unsigned int w =
        reinterpret_cast<const unsigned int*>(csr16 + (size_t)wid * kStride)[lane & 31];

    const unsigned int hw = reinterpret_cast<const unsigned int*>(out)[(size_t)wid * 128 + lane];

    float a0 = 0.f, a1 = 0.f;
    int e = 0;
    for (; e + 8 <= deg; e += 8) {
        const int p0 = __builtin_amdgcn_readlane(w, (e >> 1));
        const int p1 = __builtin_amdgcn_readlane(w, (e >> 1) + 1);
        const int p2 = __builtin_amdgcn_readlane(w, (e >> 1) + 2);
        const int p3 = __builtin_amdgcn_readlane(w, (e >> 1) + 3);
        const unsigned int w0 = hvb[(size_t)(p0 & 0xffff) * 64 + lane];
        const unsigned int w1 = hvb[(size_t)((p0 >> 16) & 0xffff) * 64 + lane];
        const unsigned int w2 = hvb[(size_t)(p1 & 0xffff) * 64 + lane];
        const unsigned int w3 = hvb[(size_t)((p1 >> 16) & 0xffff) * 64 + lane];
        const unsigned int w4 = hvb[(size_t)(p2 & 0xffff) * 64 + lane];
        const unsigned int w5 = hvb[(size_t)((p2 >> 16) & 0xffff) * 64 + lane];
        const unsigned int w6 = hvb[(size_t)(p3 & 0xffff) * 64 + lane];
        const unsigned int w7 = hvb[(size_t)((p3 >> 16) & 0xffff) * 64 + lane];
        a0 += __uint_as_float(w0 << 16) + __uint_as_float(w1 << 16)
            + __uint_as_float(w2 << 16) + __uint_as_float(w3 << 16)
            + __uint_as_float(w4 << 16) + __uint_as_float(w5 << 16)
            + __uint_as_float(w6 << 16) + __uint_as_float(w7 << 16);
        a1 += __uint_as_float(w0 & 0xffff0000u) + __uint_as_float(w1 & 0xffff0000u)
            + __uint_as_float(w2 & 0xffff0000u) + __uint_as_float(w3 & 0xffff0000u)
            + __uint_as_float(w4 & 0xffff0000u) + __uint_as_float(w5 & 0xffff0000u)
            + __uint_as_float(w6 & 0xffff0000u) + __uint_as_float(w7 & 0xffff0000u);
    }
    for (; e + 4 <= deg; e += 4) {
        const int p0 = __builtin_amdgcn_readlane(w, e >> 1);
        const int p1 = __builtin_amdgcn_readlane(w, (e >> 1) + 1);
        const unsigned int w0 = hvb[(size_t)(p0 & 0xffff) * 64 + lane];
        const unsigned int w1 = hvb[(size_t)((p0 >> 16) & 0xffff) * 64 + lane];
        const unsigned int w2 = hvb[(size_t)(p1 & 0xffff) * 64 + lane];
        const unsigned int w3 = hvb[(size_t)((p1 >> 16) & 0xffff) * 64 + lane];
        a0 += __uint_as_float(w0 << 16) + __uint_as_float(w1 << 16)
            + __uint_as_float(w2 << 16) + __uint_as_float(w3 << 16);
        a1 += __uint_as_float(w0 & 0xffff0000u) + __uint_as_float(w1 & 0xffff0000u)
            + __uint_as_float(w2 & 0xffff0000u) + __uint_as_float(w3 & 0xffff0000u);
    }
    for (; e < deg; ++e) {
        const int p = __builtin_amdgcn_readlane(w, e >> 1);
        const int s = (e & 1) ? ((p >> 16) & 0xffff) : (p & 0xffff);
        const unsigned int wv = hvb[(size_t)s * 64 + lane];
        a0 += __uint_as_float(wv << 16);
        a1 += __uint_as_float(wv & 0xffff0000u);
    }

    const float b0 = __uint_as_float(hw << 16);
    const float b1 = __uint_as_float(hw & 0xffff0000u);

    float2* out2 = reinterpret_cast<float2*>(out);
    float2 o;
    o.x = fmaxf(b0 + a0, 0.f);
    o.y = fmaxf(b1 + a1, 0.f);
    out2[(size_t)wid * 64 + lane] = o;
}

extern "C" void kernel_launch(void* const* d_in, const int* in_sizes, int n_in,
                              void* d_out, int out_size, void* d_ws, size_t ws_size,
                              hipStream_t stream) {
    const float* H    = (const float*)d_in[0];
    const float* U    = (const float*)d_in[1];
    const float* V    = (const float*)d_in[2];
    const int*   esrc = (const int*)d_in[3];
    const int*   edst = (const int*)d_in[4];

    float* out = (float*)d_out;

    // Workspace layout (~22.8 MB; proven available)
    char* p = (char*)d_ws;
    unsigned short* hvb  = (unsigned short*)p;  p += (size_t)kNodes * kD * 2;        // 12.8 MB
    short*          BTf  = (short*)p;           p += (size_t)256 * kD * 2;           // 64 KB
    int*            bcnt = (int*)p;             p += (size_t)kNB * 32 * 4;           // 51.2 KB
    unsigned int*   barr = (unsigned int*)p;    p += (size_t)kNB * kCap * 4;         // 3.28 MB
    int*            cursor = (int*)p;           p += (size_t)kNodes * 4;             // 200 KB
    unsigned short* csr16  = (unsigned short*)p;p += (size_t)kNodes * kStride * 2;   // 6.4 MB

    // B pack (frag-major) + bucket-counter zeroing
    pack_init<<<128, 512, 0, stream>>>(U, V, BTf, bcnt);

    // Fused: persistent-wave MFMA dual GEMM (pipelined, packed stores) + bucketing
    gemm_bucket<<<kTotalBlocks, 256, 0, stream>>>(H, BTf, esrc, edst,
                                                  (unsigned short*)d_out, hvb, bcnt, barr);

    // Bucket -> fixed-stride CSR (LDS-atomic counting sort)
    bucket_sort<<<kNB, 256, 0, stream>>>(bcnt, barr, cursor, csr16);

    // Aggregate + fused ReLU
    aggregate_relu<<<(kNodes * 64 + 255) / 256, 256, 0, stream>>>(
        (const unsigned int*)hvb, cursor, csr16, out);
}

// Round 11
// 63.424 us; speedup vs baseline: 1.1149x; 1.1149x over previous
//
#include <hip/hip_runtime.h>
#include <hip/hip_bf16.h>

constexpr int kNodes  = 50000;
constexpr int kEdges  = 600000;
constexpr int kD      = 128;
constexpr int kStrips = kNodes / 16;               // 3125 gemm strips
constexpr int kStride = 64;                        // CSR segment capacity (max deg ~35)

// Bucket geometry: per-(block,bucket) PRIVATE cells -> zero global atomics.
constexpr int kNB        = 400;                    // coarse dst-buckets
constexpr int kNPB       = 125;                    // nodes per bucket
constexpr int kEPB       = 4096;                   // edges per bucket-role block
constexpr int kBktBlocks = (kEdges + kEPB - 1) / kEPB;    // 147
constexpr int kCellCap   = 32;                     // slots/cell (lambda=10.2, P(>32)~1e-8)
constexpr int kCellStr   = 148;                    // padded 147 (cnt_arr row stride)
constexpr int kPackBlocks  = 128;                  // 128*256 = 32768 = 256*kD
constexpr int kPrepBlocks  = kBktBlocks + kPackBlocks;    // 275
constexpr int kGemmBlocks  = 768;                  // persistent gemm blocks
constexpr int kK2Blocks    = kNB + kGemmBlocks;    // 1168

typedef __attribute__((ext_vector_type(8))) short  short8;   // 8 bf16 (A/B frag)
typedef __attribute__((ext_vector_type(4))) float  f32x4;    // C/D frag

__device__ __forceinline__ unsigned short f2bfu(float x) {
    __hip_bfloat16 h = __float2bfloat16(x);                   // RTNE
    return (unsigned short)__builtin_bit_cast(short, h);
}
__device__ __forceinline__ short f2bf(float x) {
    return __builtin_bit_cast(short, __float2bfloat16(x));
}

// ---------------------------------------------------------------------------
// Kernel 1: prep = BTf pack (frag-major, R7 layout) || edge bucket-scatter.
// Bucket role: block bid owns edges [bid*4096, ...); all slot allocation is
// LDS-local (cur[400] starts at 0 per block -> cell-local slots).  Output:
//   barr[bid][bucket][slot<32] = (dst_local<<16 | src)   (plain stores)
//   cnt_arr[bucket][bid]       = cell count              (plain stores)
// No bcnt, no memset, no global atomics anywhere.
// ---------------------------------------------------------------------------
__global__ __launch_bounds__(256) void prep(const float* __restrict__ U,
                                            const float* __restrict__ V,
                                            const int* __restrict__ esrc,
                                            const int* __restrict__ edst,
                                            short* __restrict__ BTf,
                                            unsigned short* __restrict__ cnt_arr,
                                            unsigned int* __restrict__ barr) {
    const int bid = blockIdx.x;

    if (bid < kBktBlocks) {
        __shared__ int cur[kNB];
        for (int i = threadIdx.x; i < kNB; i += 256) cur[i] = 0;
        __syncthreads();

        const int e0 = bid * kEPB;
        int myd[16], mys[16];
#pragma unroll
        for (int i = 0; i < 16; ++i) {              // 32 loads issued up front
            const int e = e0 + i * 256 + (int)threadIdx.x;
            myd[i] = (e < kEdges) ? edst[e] : -1;
            mys[i] = (e < kEdges) ? esrc[e] : 0;
        }
#pragma unroll
        for (int i = 0; i < 16; ++i) {
            if (myd[i] >= 0) {
                const int b = myd[i] / kNPB;
                const int slot = atomicAdd(&cur[b], 1);           // LDS atomic
                if (slot < kCellCap)
                    barr[((size_t)bid * kNB + b) * kCellCap + slot] =
                        ((unsigned)(myd[i] - b * kNPB) << 16) | (unsigned)mys[i];
            }
        }
        __syncthreads();
        for (int i = threadIdx.x; i < kNB; i += 256)
            cnt_arr[(size_t)i * kCellStr + bid] =
                (unsigned short)min(cur[i], kCellCap);
        return;
    }

    // ---- pack role: BTf fragment-major ----
    const int g = (bid - kBktBlocks) * 256 + (int)threadIdx.x;    // 0..32767
    const int c = g >> 7;          // 0..255 (global output col)
    const int k = g & 127;
    const float x = (c < kD) ? U[k * kD + c] : V[k * kD + (c - kD)];
    const int q  = c >> 6;
    const int n  = (c >> 4) & 3;
    const int m  = c & 15;
    const int t  = k >> 5;
    const int kg = (k >> 3) & 3;
    const int ko = k & 7;
    const int lane = kg * 16 + m;
    BTf[((((q * 4 + n) * 4 + t) * 64 + lane) << 3) + ko] = f2bf(x);
}

// ---------------------------------------------------------------------------
// Kernel 2: gemm_sort = sort role (400 blocks) || gemm role (768 blocks).
//
// sort role: bucket b; thread t<147 drains cell (t, b): per entry, LDS-atomic
// per-node slot -> csr16[node*64+slot] (16KB L2-local region).  cursor[n] =
// exact degree.  No global atomics.
//
// gemm role: R10-proven persistent-wave MFMA dual GEMM: B-frags register-
// resident (loaded once), swapped-operand mfma(bf,a) -> row-major thread
// tile -> packed 8B stores, 2-deep strip pipeline.
// mfma_f32_16x16x32_bf16 D layout: col=lane&15 -> out row, (lane>>4)*4+j ->
// out col (m89-verified).  hu -> bf16 first 256B of d_out rows; hv -> ws.
// ---------------------------------------------------------------------------
__global__ __launch_bounds__(256) void gemm_sort(const float* __restrict__ H,
                                                 const short* __restrict__ BTf,
                                                 const unsigned short* __restrict__ cnt_arr,
                                                 const unsigned int* __restrict__ barr,
                                                 unsigned short* __restrict__ outb, // d_out u16
                                                 unsigned short* __restrict__ hvb,
                                                 int* __restrict__ cursor,
                                                 unsigned short* __restrict__ csr16) {
    const int bid = blockIdx.x;

    if (bid < kNB) {
        // ---- sort role: bucket b = bid ----
        __shared__ int cnt[kNPB];
        for (int i = threadIdx.x; i < kNPB; i += 256) cnt[i] = 0;
        __syncthreads();

        const int b = bid;
        const int t = (int)threadIdx.x;
        if (t < kBktBlocks) {
            const int c = cnt_arr[(size_t)b * kCellStr + t];
            const unsigned int* cell = barr + ((size_t)t * kNB + b) * kCellCap;
            for (int j = 0; j < c; ++j) {
                const unsigned int p = cell[j];
                const int dl  = (int)(p >> 16);
                const int src = (int)(p & 0xffffu);
                const int slot = atomicAdd(&cnt[dl], 1);          // LDS atomic
                if (slot < kStride)
                    csr16[((size_t)b * kNPB + dl) * kStride + slot] = (unsigned short)src;
            }
        }
        __syncthreads();
        for (int i = threadIdx.x; i < kNPB; i += 256)
            cursor[b * kNPB + i] = cnt[i];
        return;
    }

    // ---- gemm role: persistent wave, register-resident B ----
    const int g  = bid - kNB;                        // 0..767
    const int s0 = (int)((long)g       * kStrips / kGemmBlocks);
    const int s1 = (int)((long)(g + 1) * kStrips / kGemmBlocks);
    const int quad = threadIdx.x >> 6;               // 0..3 (64-col quarter)
    const int lane = threadIdx.x & 63;
    const int m  = lane & 15;
    const int kg = lane >> 4;                        // 0..3

    const short8* bq = reinterpret_cast<const short8*>(BTf)
                     + ((size_t)quad * 16) * 64 + lane;
    short8 bf[4][4];
#pragma unroll
    for (int n = 0; n < 4; ++n)
#pragma unroll
        for (int t = 0; t < 4; ++t)
            bf[n][t] = bq[(n * 4 + t) * 64];

    auto load_ha = [&](int s, float4 (&ha)[4][2]) {
        const float* hbase = H + ((long)s * 16 + m) * kD + kg * 8;
#pragma unroll
        for (int t = 0; t < 4; ++t) {
            ha[t][0] = *reinterpret_cast<const float4*>(hbase + t * 32);
            ha[t][1] = *reinterpret_cast<const float4*>(hbase + t * 32 + 4);
        }
    };

    auto compute_store = [&](int s, float4 (&ha)[4][2]) {
        short8 a[4];
#pragma unroll
        for (int t = 0; t < 4; ++t) {
            a[t][0] = f2bf(ha[t][0].x); a[t][1] = f2bf(ha[t][0].y);
            a[t][2] = f2bf(ha[t][0].z); a[t][3] = f2bf(ha[t][0].w);
            a[t][4] = f2bf(ha[t][1].x); a[t][5] = f2bf(ha[t][1].y);
            a[t][6] = f2bf(ha[t][1].z); a[t][7] = f2bf(ha[t][1].w);
        }

        f32x4 acc[4];
#pragma unroll
        for (int i = 0; i < 4; ++i) acc[i] = (f32x4){0.f, 0.f, 0.f, 0.f};
#pragma unroll
        for (int t = 0; t < 4; ++t)
#pragma unroll
            for (int n = 0; n < 4; ++n)   // swapped operands -> row-major tile
                acc[n] = __builtin_amdgcn_mfma_f32_16x16x32_bf16(bf[n][t], a[t], acc[n], 0, 0, 0);

        const long row0 = (long)s * 16;
        if (quad < 2) {      // hu -> d_out rows (bf16, first 256B of each row)
            unsigned short* rowp = outb + (size_t)(row0 + m) * 256 + quad * 64 + kg * 4;
#pragma unroll
            for (int n = 0; n < 4; ++n) {
                uint2 pk;
                pk.x = ((unsigned)f2bfu(acc[n][1]) << 16) | f2bfu(acc[n][0]);
                pk.y = ((unsigned)f2bfu(acc[n][3]) << 16) | f2bfu(acc[n][2]);
                *reinterpret_cast<uint2*>(rowp + n * 16) = pk;
            }
        } else {             // hv -> ws (bf16)
            unsigned short* rowp = hvb + (size_t)(row0 + m) * kD + (quad - 2) * 64 + kg * 4;
#pragma unroll
            for (int n = 0; n < 4; ++n) {
                uint2 pk;
                pk.x = ((unsigned)f2bfu(acc[n][1]) << 16) | f2bfu(acc[n][0]);
                pk.y = ((unsigned)f2bfu(acc[n][3]) << 16) | f2bfu(acc[n][2]);
                *reinterpret_cast<uint2*>(rowp + n * 16) = pk;
            }
        }
    };

    float4 haA[4][2], haB[4][2];
    int s = s0;
    if (s >= s1) return;
    load_ha(s, haA);
    for (; s + 1 < s1; s += 2) {
        load_ha(s + 1, haB);
        compute_store(s, haA);
        if (s + 2 < s1) load_ha(s + 2, haA);
        compute_store(s + 1, haB);
    }
    if (s < s1) compute_store(s, haA);
}

// ---------------------------------------------------------------------------
// Kernel 3: aggregation + ReLU (R10-proven).  One wave per node; neighbor
// list fetched as one dword per lane; readlane broadcasts packed pairs; hv
// rows bf16 (one dword per lane = features 2l,2l+1); 8-wide gather unroll.
// hu read as bf16 from d_out row's first 256B, overwritten with f32 result.
// ---------------------------------------------------------------------------
__global__ __launch_bounds__(256) void aggregate_relu(const unsigned int* __restrict__ hvb,
                                                      const int* __restrict__ cursor,
                                                      const unsigned short* __restrict__ csr16,
                                                      float* __restrict__ out) {
    const int wid  = (int)((blockIdx.x * (long)blockDim.x + threadIdx.x) >> 6);
    const int lane = threadIdx.x & 63;
    if (wid >= kNodes) return;

    const unsigned int hw = reinterpret_cast<const unsigned int*>(out)[(size_t)wid * 128 + lane];
    const int deg = min(cursor[wid], kStride);          // wave-uniform
    const unsigned int w =
        reinterpret_cast<const unsigned int*>(csr16 + (size_t)wid * kStride)[lane & 31];

    float a0 = 0.f, a1 = 0.f;
    int e = 0;
    for (; e + 8 <= deg; e += 8) {
        const int p0 = __builtin_amdgcn_readlane(w, (e >> 1));
        const int p1 = __builtin_amdgcn_readlane(w, (e >> 1) + 1);
        const int p2 = __builtin_amdgcn_readlane(w, (e >> 1) + 2);
        const int p3 = __builtin_amdgcn_readlane(w, (e >> 1) + 3);
        const unsigned int w0 = hvb[(size_t)(p0 & 0xffff) * 64 + lane];
        const unsigned int w1 = hvb[(size_t)((p0 >> 16) & 0xffff) * 64 + lane];
        const unsigned int w2 = hvb[(size_t)(p1 & 0xffff) * 64 + lane];
        const unsigned int w3 = hvb[(size_t)((p1 >> 16) & 0xffff) * 64 + lane];
        const unsigned int w4 = hvb[(size_t)(p2 & 0xffff) * 64 + lane];
        const unsigned int w5 = hvb[(size_t)((p2 >> 16) & 0xffff) * 64 + lane];
        const unsigned int w6 = hvb[(size_t)(p3 & 0xffff) * 64 + lane];
        const unsigned int w7 = hvb[(size_t)((p3 >> 16) & 0xffff) * 64 + lane];
        a0 += __uint_as_float(w0 << 16) + __uint_as_float(w1 << 16)
            + __uint_as_float(w2 << 16) + __uint_as_float(w3 << 16)
            + __uint_as_float(w4 << 16) + __uint_as_float(w5 << 16)
            + __uint_as_float(w6 << 16) + __uint_as_float(w7 << 16);
        a1 += __uint_as_float(w0 & 0xffff0000u) + __uint_as_float(w1 & 0xffff0000u)
            + __uint_as_float(w2 & 0xffff0000u) + __uint_as_float(w3 & 0xffff0000u)
            + __uint_as_float(w4 & 0xffff0000u) + __uint_as_float(w5 & 0xffff0000u)
            + __uint_as_float(w6 & 0xffff0000u) + __uint_as_float(w7 & 0xffff0000u);
    }
    for (; e + 4 <= deg; e += 4) {
        const int p0 = __builtin_amdgcn_readlane(w, e >> 1);
        const int p1 = __builtin_amdgcn_readlane(w, (e >> 1) + 1);
        const unsigned int w0 = hvb[(size_t)(p0 & 0xffff) * 64 + lane];
        const unsigned int w1 = hvb[(size_t)((p0 >> 16) & 0xffff) * 64 + lane];
        const unsigned int w2 = hvb[(size_t)(p1 & 0xffff) * 64 + lane];
        const unsigned int w3 = hvb[(size_t)((p1 >> 16) & 0xffff) * 64 + lane];
        a0 += __uint_as_float(w0 << 16) + __uint_as_float(w1 << 16)
            + __uint_as_float(w2 << 16) + __uint_as_float(w3 << 16);
        a1 += __uint_as_float(w0 & 0xffff0000u) + __uint_as_float(w1 & 0xffff0000u)
            + __uint_as_float(w2 & 0xffff0000u) + __uint_as_float(w3 & 0xffff0000u);
    }
    for (; e < deg; ++e) {
        const int p = __builtin_amdgcn_readlane(w, e >> 1);
        const int s = (e & 1) ? ((p >> 16) & 0xffff) : (p & 0xffff);
        const unsigned int wv = hvb[(size_t)s * 64 + lane];
        a0 += __uint_as_float(wv << 16);
        a1 += __uint_as_float(wv & 0xffff0000u);
    }

    const float b0 = __uint_as_float(hw << 16);
    const float b1 = __uint_as_float(hw & 0xffff0000u);

    float2* out2 = reinterpret_cast<float2*>(out);
    float2 o;
    o.x = fmaxf(b0 + a0, 0.f);
    o.y = fmaxf(b1 + a1, 0.f);
    out2[(size_t)wid * 64 + lane] = o;
}

extern "C" void kernel_launch(void* const* d_in, const int* in_sizes, int n_in,
                              void* d_out, int out_size, void* d_ws, size_t ws_size,
                              hipStream_t stream) {
    const float* H    = (const float*)d_in[0];
    const float* U    = (const float*)d_in[1];
    const float* V    = (const float*)d_in[2];
    const int*   esrc = (const int*)d_in[3];
    const int*   edst = (const int*)d_in[4];

    float* out = (float*)d_out;

    // Workspace layout (~27.1 MB; ws is ~256 MB per the harness poison size)
    char* p = (char*)d_ws;
    unsigned short* hvb     = (unsigned short*)p;  p += (size_t)kNodes * kD * 2;            // 12.8 MB
    short*          BTf     = (short*)p;           p += (size_t)256 * kD * 2;               // 64 KB
    unsigned short* cnt_arr = (unsigned short*)p;  p += (size_t)kNB * kCellStr * 2;         // 118 KB
    unsigned int*   barr    = (unsigned int*)p;    p += (size_t)kBktBlocks * kNB * kCellCap * 4; // 7.5 MB
    int*            cursor  = (int*)p;             p += (size_t)kNodes * 4;                 // 200 KB
    unsigned short* csr16   = (unsigned short*)p;  p += (size_t)kNodes * kStride * 2;       // 6.4 MB

    // K1: BTf pack || atomic-free edge bucket-scatter
    prep<<<kPrepBlocks, 256, 0, stream>>>(U, V, esrc, edst, BTf, cnt_arr, barr);

    // K2: cell-drain sort (400 blocks) || persistent MFMA dual GEMM (768 blocks)
    gemm_sort<<<kK2Blocks, 256, 0, stream>>>(H, BTf, cnt_arr, barr,
                                             (unsigned short*)d_out, hvb, cursor, csr16);

    // K3: aggregate + fused ReLU
    aggregate_relu<<<(kNodes * 64 + 255) / 256, 256, 0, stream>>>(
        (const unsigned int*)hvb, cursor, csr16, out);
}

// Round 12
// 61.396 us; speedup vs baseline: 1.1517x; 1.0330x over previous
//
#include <hip/hip_runtime.h>
#include <hip/hip_bf16.h>

constexpr int kNodes  = 50000;
constexpr int kEdges  = 600000;
constexpr int kD      = 128;
constexpr int kStrips = kNodes / 16;               // 3125 gemm strips

// Bucket geometry: per-(block,bucket) PRIVATE cells -> zero global atomics.
constexpr int kNB        = 400;                    // coarse dst-buckets
constexpr int kNPB       = 125;                    // nodes per bucket
constexpr int kEPB       = 4096;                   // edges per scatter block
constexpr int kBktBlocks = (kEdges + kEPB - 1) / kEPB;    // 147
constexpr int kCellCap   = 32;                     // slots/cell (lambda=10.2; proven R11)
constexpr int kCellStr   = 148;                    // cnt_arr row stride
constexpr int kListCap   = 64;                     // per-node list cap (max deg ~35)
constexpr int kGemmBlocks  = 768;                  // persistent gemm blocks
constexpr int kK1Blocks    = kBktBlocks + kGemmBlocks;    // 915

typedef __attribute__((ext_vector_type(8))) short  short8;   // 8 bf16 (A/B frag)
typedef __attribute__((ext_vector_type(4))) float  f32x4;    // C/D frag

__device__ __forceinline__ unsigned short f2bfu(float x) {
    __hip_bfloat16 h = __float2bfloat16(x);                   // RTNE
    return (unsigned short)__builtin_bit_cast(short, h);
}
__device__ __forceinline__ short f2bf(float x) {
    return __builtin_bit_cast(short, __float2bfloat16(x));
}

// ---------------------------------------------------------------------------
// Kernel 1: gemm_bucket = persistent MFMA dual GEMM || edge bucket-scatter.
//
// gemm role (R10-proven core): B-frags now loaded DIRECTLY from U/V (128
// strided f32 loads per wave, one-time, U/V = 128KB L2-resident) — removes
// the BTf pack kernel and its serial dependency.  B register-resident;
// swapped-operand mfma(bf, a) -> thread owns output ROW row0+m, 4 consecutive
// cols -> packed 8B uint2 stores; 2-deep strip software pipeline.
// mfma_f32_16x16x32_bf16 D layout: col=lane&15 -> out row, (lane>>4)*4+j ->
// out col (m89-verified, regression-tested by absmax 1.0 since R3).
// hu -> bf16 into first 256B of each d_out row; hv -> bf16 ws.
//
// scatter role (R11-proven): block bid owns 4096 edges; slot allocation is
// LDS-local -> per-(block,bucket) private cells; plain global stores only.
//   barr[bid][bucket][slot<32] = (dst_local<<16 | src)
//   cnt_arr[bucket][bid]       = cell count
// ---------------------------------------------------------------------------
__global__ __launch_bounds__(256) void gemm_bucket(const float* __restrict__ H,
                                                   const float* __restrict__ U,
                                                   const float* __restrict__ V,
                                                   const int* __restrict__ esrc,
                                                   const int* __restrict__ edst,
                                                   unsigned short* __restrict__ outb, // d_out u16
                                                   unsigned short* __restrict__ hvb,
                                                   unsigned short* __restrict__ cnt_arr,
                                                   unsigned int* __restrict__ barr) {
    const int bid = blockIdx.x;

    if (bid < kBktBlocks) {
        // ---- scatter role ----
        __shared__ int cur[kNB];
        for (int i = threadIdx.x; i < kNB; i += 256) cur[i] = 0;
        __syncthreads();

        const int e0 = bid * kEPB;
        int myd[16], mys[16];
#pragma unroll
        for (int i = 0; i < 16; ++i) {              // 32 loads issued up front
            const int e = e0 + i * 256 + (int)threadIdx.x;
            myd[i] = (e < kEdges) ? edst[e] : -1;
            mys[i] = (e < kEdges) ? esrc[e] : 0;
        }
#pragma unroll
        for (int i = 0; i < 16; ++i) {
            if (myd[i] >= 0) {
                const int b = myd[i] / kNPB;
                const int slot = atomicAdd(&cur[b], 1);           // LDS atomic
                if (slot < kCellCap)
                    barr[((size_t)bid * kNB + b) * kCellCap + slot] =
                        ((unsigned)(myd[i] - b * kNPB) << 16) | (unsigned)mys[i];
            }
        }
        __syncthreads();
        for (int i = threadIdx.x; i < kNB; i += 256)
            cnt_arr[(size_t)i * kCellStr + bid] =
                (unsigned short)min(cur[i], kCellCap);
        return;
    }

    // ---- gemm role: persistent wave, register-resident B ----
    const int g  = bid - kBktBlocks;                 // 0..767
    const int s0 = (int)((long)g       * kStrips / kGemmBlocks);
    const int s1 = (int)((long)(g + 1) * kStrips / kGemmBlocks);
    const int quad = threadIdx.x >> 6;               // 0..3 (64-col quarter)
    const int lane = threadIdx.x & 63;
    const int m  = lane & 15;
    const int kg = lane >> 4;                        // 0..3

    // B-frags straight from U/V (one-time transpose-gather, L2-resident).
    // bf[n][t][j] = W[k = t*32+kg*8+j][col = (quad&1)*64 + n*16 + m]
    const float* W = (quad < 2) ? U : V;
    const int cb = (quad & 1) * 64 + m;
    short8 bf[4][4];
#pragma unroll
    for (int n = 0; n < 4; ++n)
#pragma unroll
        for (int t = 0; t < 4; ++t) {
#pragma unroll
            for (int j = 0; j < 8; ++j)
                bf[n][t][j] = f2bf(W[(size_t)(t * 32 + kg * 8 + j) * kD + cb + n * 16]);
        }

    auto load_ha = [&](int s, float4 (&ha)[4][2]) {
        const float* hbase = H + ((long)s * 16 + m) * kD + kg * 8;
#pragma unroll
        for (int t = 0; t < 4; ++t) {
            ha[t][0] = *reinterpret_cast<const float4*>(hbase + t * 32);
            ha[t][1] = *reinterpret_cast<const float4*>(hbase + t * 32 + 4);
        }
    };

    auto compute_store = [&](int s, float4 (&ha)[4][2]) {
        short8 a[4];
#pragma unroll
        for (int t = 0; t < 4; ++t) {
            a[t][0] = f2bf(ha[t][0].x); a[t][1] = f2bf(ha[t][0].y);
            a[t][2] = f2bf(ha[t][0].z); a[t][3] = f2bf(ha[t][0].w);
            a[t][4] = f2bf(ha[t][1].x); a[t][5] = f2bf(ha[t][1].y);
            a[t][6] = f2bf(ha[t][1].z); a[t][7] = f2bf(ha[t][1].w);
        }

        f32x4 acc[4];
#pragma unroll
        for (int i = 0; i < 4; ++i) acc[i] = (f32x4){0.f, 0.f, 0.f, 0.f};
#pragma unroll
        for (int t = 0; t < 4; ++t)
#pragma unroll
            for (int n = 0; n < 4; ++n)   // swapped operands -> row-major tile
                acc[n] = __builtin_amdgcn_mfma_f32_16x16x32_bf16(bf[n][t], a[t], acc[n], 0, 0, 0);

        const long row0 = (long)s * 16;
        if (quad < 2) {      // hu -> d_out rows (bf16, first 256B of each row)
            unsigned short* rowp = outb + (size_t)(row0 + m) * 256 + quad * 64 + kg * 4;
#pragma unroll
            for (int n = 0; n < 4; ++n) {
                uint2 pk;
                pk.x = ((unsigned)f2bfu(acc[n][1]) << 16) | f2bfu(acc[n][0]);
                pk.y = ((unsigned)f2bfu(acc[n][3]) << 16) | f2bfu(acc[n][2]);
                *reinterpret_cast<uint2*>(rowp + n * 16) = pk;
            }
        } else {             // hv -> ws (bf16)
            unsigned short* rowp = hvb + (size_t)(row0 + m) * kD + (quad - 2) * 64 + kg * 4;
#pragma unroll
            for (int n = 0; n < 4; ++n) {
                uint2 pk;
                pk.x = ((unsigned)f2bfu(acc[n][1]) << 16) | f2bfu(acc[n][0]);
                pk.y = ((unsigned)f2bfu(acc[n][3]) << 16) | f2bfu(acc[n][2]);
                *reinterpret_cast<uint2*>(rowp + n * 16) = pk;
            }
        }
    };

    float4 haA[4][2], haB[4][2];
    int s = s0;
    if (s >= s1) return;
    load_ha(s, haA);
    for (; s + 1 < s1; s += 2) {
        load_ha(s + 1, haB);
        compute_store(s, haA);
        if (s + 2 < s1) load_ha(s + 2, haA);
        compute_store(s + 1, haB);
    }
    if (s < s1) compute_store(s, haA);
}

// ---------------------------------------------------------------------------
// Kernel 2: sort_aggregate.  Buckets are SELF-CONTAINED: aggregating bucket
// b's 125 nodes needs only bucket b's cells.  One 1024-thread block per
// bucket: (1) drain the 147 cells into an LDS per-node list (LDS atomics,
// 16KB); (2) barrier; (3) 16 waves aggregate 7-8 nodes each with the proven
// readlane-broadcast gather loop.  Deletes the csr16/cursor global round-trip
// (~13MB) and one dispatch.  hu read as bf16 from d_out row's first 256B,
// overwritten with the f32 result (block owns its rows exclusively).
// ---------------------------------------------------------------------------
__global__ __launch_bounds__(1024) void sort_aggregate(const unsigned int* __restrict__ hvb,
                                                       const unsigned short* __restrict__ cnt_arr,
                                                       const unsigned int* __restrict__ barr,
                                                       float* __restrict__ out) {
    __shared__ unsigned short list16[kNPB * kListCap];   // 16000 B
    __shared__ int cnt[kNPB];
    const int b = blockIdx.x;

    for (int i = threadIdx.x; i < kNPB; i += 1024) cnt[i] = 0;
    __syncthreads();

    // Phase 1: drain cells (thread t < 147 owns cell (t, b))
    const int t = (int)threadIdx.x;
    if (t < kBktBlocks) {
        const int c = cnt_arr[(size_t)b * kCellStr + t];
        const unsigned int* cell = barr + ((size_t)t * kNB + b) * kCellCap;
        for (int j = 0; j < c; ++j) {
            const unsigned int p = cell[j];
            const int dl  = (int)(p >> 16);
            const int src = (int)(p & 0xffffu);
            const int slot = atomicAdd(&cnt[dl], 1);          // LDS atomic
            if (slot < kListCap)
                list16[dl * kListCap + slot] = (unsigned short)src;
        }
    }
    __syncthreads();

    // Phase 2: aggregate.  Wave w handles nodes w, w+16, ...
    const unsigned int* list32 = reinterpret_cast<const unsigned int*>(list16);
    const int wave = (int)threadIdx.x >> 6;
    const int lane = (int)threadIdx.x & 63;
    const int n0 = b * kNPB;

    for (int dl = wave; dl < kNPB; dl += 16) {
        const int deg = min(cnt[dl], kListCap);           // wave-uniform
        const unsigned int w = list32[dl * 32 + (lane & 31)];   // whole list, 1 LDS read

        const unsigned int hw =
            reinterpret_cast<const unsigned int*>(out)[(size_t)(n0 + dl) * 128 + lane];

        float a0 = 0.f, a1 = 0.f;
        int e = 0;
        for (; e + 8 <= deg; e += 8) {
            const int p0 = __builtin_amdgcn_readlane(w, (e >> 1));
            const int p1 = __builtin_amdgcn_readlane(w, (e >> 1) + 1);
            const int p2 = __builtin_amdgcn_readlane(w, (e >> 1) + 2);
            const int p3 = __builtin_amdgcn_readlane(w, (e >> 1) + 3);
            const unsigned int w0 = hvb[(size_t)(p0 & 0xffff) * 64 + lane];
            const unsigned int w1 = hvb[(size_t)((p0 >> 16) & 0xffff) * 64 + lane];
            const unsigned int w2 = hvb[(size_t)(p1 & 0xffff) * 64 + lane];
            const unsigned int w3 = hvb[(size_t)((p1 >> 16) & 0xffff) * 64 + lane];
            const unsigned int w4 = hvb[(size_t)(p2 & 0xffff) * 64 + lane];
            const unsigned int w5 = hvb[(size_t)((p2 >> 16) & 0xffff) * 64 + lane];
            const unsigned int w6 = hvb[(size_t)(p3 & 0xffff) * 64 + lane];
            const unsigned int w7 = hvb[(size_t)((p3 >> 16) & 0xffff) * 64 + lane];
            a0 += __uint_as_float(w0 << 16) + __uint_as_float(w1 << 16)
                + __uint_as_float(w2 << 16) + __uint_as_float(w3 << 16)
                + __uint_as_float(w4 << 16) + __uint_as_float(w5 << 16)
                + __uint_as_float(w6 << 16) + __uint_as_float(w7 << 16);
            a1 += __uint_as_float(w0 & 0xffff0000u) + __uint_as_float(w1 & 0xffff0000u)
                + __uint_as_float(w2 & 0xffff0000u) + __uint_as_float(w3 & 0xffff0000u)
                + __uint_as_float(w4 & 0xffff0000u) + __uint_as_float(w5 & 0xffff0000u)
                + __uint_as_float(w6 & 0xffff0000u) + __uint_as_float(w7 & 0xffff0000u);
        }
        for (; e + 4 <= deg; e += 4) {
            const int p0 = __builtin_amdgcn_readlane(w, e >> 1);
            const int p1 = __builtin_amdgcn_readlane(w, (e >> 1) + 1);
            const unsigned int w0 = hvb[(size_t)(p0 & 0xffff) * 64 + lane];
            const unsigned int w1 = hvb[(size_t)((p0 >> 16) & 0xffff) * 64 + lane];
            const unsigned int w2 = hvb[(size_t)(p1 & 0xffff) * 64 + lane];
            const unsigned int w3 = hvb[(size_t)((p1 >> 16) & 0xffff) * 64 + lane];
            a0 += __uint_as_float(w0 << 16) + __uint_as_float(w1 << 16)
                + __uint_as_float(w2 << 16) + __uint_as_float(w3 << 16);
            a1 += __uint_as_float(w0 & 0xffff0000u) + __uint_as_float(w1 & 0xffff0000u)
                + __uint_as_float(w2 & 0xffff0000u) + __uint_as_float(w3 & 0xffff0000u);
        }
        for (; e < deg; ++e) {
            const int p = __builtin_amdgcn_readlane(w, e >> 1);
            const int s = (e & 1) ? ((p >> 16) & 0xffff) : (p & 0xffff);
            const unsigned int wv = hvb[(size_t)s * 64 + lane];
            a0 += __uint_as_float(wv << 16);
            a1 += __uint_as_float(wv & 0xffff0000u);
        }

        const float b0 = __uint_as_float(hw << 16);
        const float b1 = __uint_as_float(hw & 0xffff0000u);

        float2 o;
        o.x = fmaxf(b0 + a0, 0.f);
        o.y = fmaxf(b1 + a1, 0.f);
        reinterpret_cast<float2*>(out)[(size_t)(n0 + dl) * 64 + lane] = o;
    }
}

extern "C" void kernel_launch(void* const* d_in, const int* in_sizes, int n_in,
                              void* d_out, int out_size, void* d_ws, size_t ws_size,
                              hipStream_t stream) {
    const float* H    = (const float*)d_in[0];
    const float* U    = (const float*)d_in[1];
    const float* V    = (const float*)d_in[2];
    const int*   esrc = (const int*)d_in[3];
    const int*   edst = (const int*)d_in[4];

    float* out = (float*)d_out;

    // Workspace layout (~20.5 MB; proven available)
    char* p = (char*)d_ws;
    unsigned short* hvb     = (unsigned short*)p;  p += (size_t)kNodes * kD * 2;            // 12.8 MB
    unsigned short* cnt_arr = (unsigned short*)p;  p += (size_t)kNB * kCellStr * 2;         // 118 KB
    unsigned int*   barr    = (unsigned int*)p;    p += (size_t)kBktBlocks * kNB * kCellCap * 4; // 7.5 MB

    // K1: persistent MFMA dual GEMM (B direct from U/V) || bucket-scatter
    gemm_bucket<<<kK1Blocks, 256, 0, stream>>>(H, U, V, esrc, edst,
                                               (unsigned short*)d_out, hvb, cnt_arr, barr);

    // K2: per-bucket LDS sort + aggregate + fused ReLU
    sort_aggregate<<<kNB, 1024, 0, stream>>>((const unsigned int*)hvb, cnt_arr, barr, out);
}